// Round 2
// baseline (389.541 us; speedup 1.0000x reference)
//
#include <hip/hip_runtime.h>
#include <hip/hip_bf16.h>

// DirNet: out[k,o,idx[j],d] = SCALE * sum_i x[k,o,idx[j],i] * W[o,d,i] + b[o,d]
// (rows not in image(idx) are a straight copy of x).
// Batched B^T GEMM, bf16 MFMA (16x16x32), fp32 accumulate.

typedef __bf16  bf16x8  __attribute__((ext_vector_type(8)));
typedef float   floatx4 __attribute__((ext_vector_type(4)));

#define O_DIM 18
#define J_DIM 18
#define KB    256
#define C_DIM 512
#define BM    128
#define BN    128
#define BK    32
#define LDSS  40   // BK + 8 pad (bf16 elems) -> 80B row stride, 2-way-free b128 reads

__device__ __forceinline__ __bf16 f2bf(float f) {
    return (__bf16)f;   // RNE fptrunc; gfx950 has native cvt
}

__global__ __launch_bounds__(256, 2)
void dirnet_gemm(const float* __restrict__ x, const float* __restrict__ W,
                 const float* __restrict__ bias, const int* __restrict__ idx,
                 float* __restrict__ out)
{
    const int nt = blockIdx.x & 3;   // N tile (d):    4 x 128
    const int mt = blockIdx.x >> 2;  // M tile (k):    2 x 128
    const int j  = blockIdx.y;
    const int o  = blockIdx.z;
    const int jj = idx[j];

    __shared__ __bf16 As[BM * LDSS];
    __shared__ __bf16 Bs[BN * LDSS];

    const int tid  = threadIdx.x;
    const int srow = tid >> 2;          // 0..63  (staging row)
    const int scol = (tid & 3) << 3;    // 0,8,16,24 (staging col, elems)

    // A row (k-row) global base; row stride between k-rows = 18*18*512 floats
    const size_t xRow0      = ((size_t)((mt * BM + srow) * O_DIM + o) * J_DIM + jj) * C_DIM;
    const size_t xRowStride = (size_t)64 * O_DIM * J_DIM * C_DIM;
    const size_t wRow0      = ((size_t)(o * C_DIM + nt * BN + srow)) * C_DIM;
    const size_t wRowStride = (size_t)64 * C_DIM;

    const int lane = tid & 63;
    const int wv   = tid >> 6;
    const int mOff = (wv & 1) * 64;
    const int nOff = (wv >> 1) * 64;
    const int lrow = lane & 15;         // frag row (A: m, B: n, C/D: col=n)
    const int lk   = (lane >> 4) << 3;  // frag k offset (quad*8)

    floatx4 acc[4][4] = {};

    for (int k0 = 0; k0 < C_DIM; k0 += BK) {
        __syncthreads();
        #pragma unroll
        for (int p = 0; p < 2; ++p) {
            const float* ap = x + xRow0 + (size_t)p * xRowStride + k0 + scol;
            const float4 ua = *(const float4*)ap;
            const float4 va = *(const float4*)(ap + 4);
            const float* bp = W + wRow0 + (size_t)p * wRowStride + k0 + scol;
            const float4 ub = *(const float4*)bp;
            const float4 vb = *(const float4*)(bp + 4);

            bf16x8 sa;
            sa[0]=f2bf(ua.x); sa[1]=f2bf(ua.y); sa[2]=f2bf(ua.z); sa[3]=f2bf(ua.w);
            sa[4]=f2bf(va.x); sa[5]=f2bf(va.y); sa[6]=f2bf(va.z); sa[7]=f2bf(va.w);
            *(bf16x8*)&As[(p * 64 + srow) * LDSS + scol] = sa;

            bf16x8 sb;
            sb[0]=f2bf(ub.x); sb[1]=f2bf(ub.y); sb[2]=f2bf(ub.z); sb[3]=f2bf(ub.w);
            sb[4]=f2bf(vb.x); sb[5]=f2bf(vb.y); sb[6]=f2bf(vb.z); sb[7]=f2bf(vb.w);
            *(bf16x8*)&Bs[(p * 64 + srow) * LDSS + scol] = sb;
        }
        __syncthreads();

        bf16x8 af[4], bf[4];
        #pragma unroll
        for (int mi = 0; mi < 4; ++mi)
            af[mi] = *(const bf16x8*)&As[(mOff + mi * 16 + lrow) * LDSS + lk];
        #pragma unroll
        for (int ni = 0; ni < 4; ++ni)
            bf[ni] = *(const bf16x8*)&Bs[(nOff + ni * 16 + lrow) * LDSS + lk];

        #pragma unroll
        for (int mi = 0; mi < 4; ++mi)
            #pragma unroll
            for (int ni = 0; ni < 4; ++ni)
                acc[mi][ni] = __builtin_amdgcn_mfma_f32_16x16x32_bf16(
                    af[mi], bf[ni], acc[mi][ni], 0, 0, 0);
    }

    // Epilogue: C/D layout col = lane&15 (n), row = (lane>>4)*4 + r (m)
    const float scale = 0.04419417382415922f;  // 1/sqrt(512), LR_MUL = 1
    const int rbase = (lane >> 4) << 2;
    #pragma unroll
    for (int ni = 0; ni < 4; ++ni) {
        const int d  = nt * BN + nOff + ni * 16 + lrow;
        const float bv = bias[o * C_DIM + d];
        #pragma unroll
        for (int mi = 0; mi < 4; ++mi) {
            #pragma unroll
            for (int r = 0; r < 4; ++r) {
                const int kr = mt * BM + mOff + mi * 16 + rbase + r;
                out[((size_t)(kr * O_DIM + o) * J_DIM + jj) * C_DIM + d] =
                    acc[mi][ni][r] * scale + bv;
            }
        }
    }
}

// Rows jj not present in idx keep their x values. With idx = arange(18) this
// kernel does no memory traffic (membership always true -> early exit).
__global__ void copy_nonsel(const float* __restrict__ x, const int* __restrict__ idx,
                            float* __restrict__ out)
{
    const int jj = blockIdx.x;
    const int o  = blockIdx.y;
    bool member = false;
    for (int t = 0; t < J_DIM; ++t) member = member || (idx[t] == jj);
    if (member) return;
    const int tid = threadIdx.x;
    for (int k = 0; k < KB; ++k) {
        const size_t base = ((size_t)(k * O_DIM + o) * J_DIM + jj) * C_DIM;
        for (int c = tid * 4; c < C_DIM; c += 256 * 4) {
            *(float4*)&out[base + c] = *(const float4*)&x[base + c];
        }
    }
}

extern "C" void kernel_launch(void* const* d_in, const int* in_sizes, int n_in,
                              void* d_out, int out_size, void* d_ws, size_t ws_size,
                              hipStream_t stream) {
    const float* x   = (const float*)d_in[0];
    const float* W   = (const float*)d_in[1];
    const float* b   = (const float*)d_in[2];
    const int*   idx = (const int*)d_in[3];
    float* out = (float*)d_out;

    dim3 grid(8, J_DIM, O_DIM);   // (2 mt * 4 nt), j, o  -> 2592 blocks
    dirnet_gemm<<<grid, 256, 0, stream>>>(x, W, b, idx, out);
    copy_nonsel<<<dim3(J_DIM, O_DIM), 256, 0, stream>>>(x, idx, out);
}